// Round 1
// baseline (1122.668 us; speedup 1.0000x reference)
//
#include <hip/hip_runtime.h>
#include <math.h>

#define DD 64
#define HH 8
#define KORD 4

// ---------- CSR build ----------
__global__ void k_count(const int* __restrict__ dst, int E, int* __restrict__ deg) {
    int i = blockIdx.x * 256 + threadIdx.x;
    if (i < E) atomicAdd(&deg[dst[i]], 1);
}

__global__ void k_blocksum(const int* __restrict__ deg, int n, int* __restrict__ bsum) {
    __shared__ int s[256];
    int i = blockIdx.x * 256 + threadIdx.x;
    s[threadIdx.x] = (i < n) ? deg[i] : 0;
    __syncthreads();
    for (int off = 128; off > 0; off >>= 1) {
        if (threadIdx.x < off) s[threadIdx.x] += s[threadIdx.x + off];
        __syncthreads();
    }
    if (threadIdx.x == 0) bsum[blockIdx.x] = s[0];
}

__global__ void k_scan_bsum(int* __restrict__ bsum, int nb) {
    __shared__ int s[256];
    int t = threadIdx.x;
    int v = (t < nb) ? bsum[t] : 0;
    s[t] = v;
    __syncthreads();
    for (int off = 1; off < 256; off <<= 1) {
        int tmp = (t >= off) ? s[t - off] : 0;
        __syncthreads();
        s[t] += tmp;
        __syncthreads();
    }
    if (t < nb) bsum[t] = s[t] - v;  // exclusive
}

__global__ void k_scan_final(const int* __restrict__ deg, const int* __restrict__ bsum,
                             int n, int E, int* __restrict__ offsets,
                             int* __restrict__ cursor, float* __restrict__ dinv) {
    __shared__ int s[256];
    int t = threadIdx.x, i = blockIdx.x * 256 + t;
    int v = (i < n) ? deg[i] : 0;
    s[t] = v;
    __syncthreads();
    for (int off = 1; off < 256; off <<= 1) {
        int tmp = (t >= off) ? s[t - off] : 0;
        __syncthreads();
        s[t] += tmp;
        __syncthreads();
    }
    if (i < n) {
        int excl = s[t] - v + bsum[blockIdx.x];
        offsets[i] = excl;
        cursor[i] = excl;
        int dv = v < 1 ? 1 : v;
        dinv[i] = 1.0f / sqrtf((float)dv);
    }
    if (i == 0) offsets[n] = E;
}

__global__ void k_scatter(const int* __restrict__ dst, int E, int* __restrict__ cursor,
                          int* __restrict__ eperm) {
    int i = blockIdx.x * 256 + threadIdx.x;
    if (i < E) {
        int p = atomicAdd(&cursor[dst[i]], 1);
        eperm[p] = i;
    }
}

// ---------- pass 1: Tx1 = lap_mul(h), agg = sum ew*h[src] (fused, shares gathers) ----------
__global__ void k_pass1(const int* __restrict__ offsets, const int* __restrict__ eperm,
                        const int* __restrict__ src, const float* __restrict__ ew,
                        const float* __restrict__ dinv, const float* __restrict__ h,
                        int n, float* __restrict__ Tx1, float* __restrict__ agg) {
    int w = threadIdx.x >> 6, lane = threadIdx.x & 63;
    int node = blockIdx.x * 4 + w;
    if (node >= n) return;
    int beg = offsets[node], end = offsets[node + 1];
    float dn = dinv[node];
    float aL = 0.f, aG = 0.f;
    for (int e2 = beg; e2 < end; ++e2) {
        int eid = eperm[e2];
        int s = src[eid];
        float v = h[s * DD + lane];
        aL += (-dn * dinv[s]) * v;
        aG += ew[eid] * v;
    }
    Tx1[node * DD + lane] = aL;
    agg[node * DD + lane] = aG;
}

// ---------- generic: out = alpha * lap_mul(x) + beta * prev ----------
__global__ void k_lap(const int* __restrict__ offsets, const int* __restrict__ eperm,
                      const int* __restrict__ src, const float* __restrict__ dinv,
                      const float* __restrict__ x, const float* __restrict__ prev,
                      float alpha, float beta, int n, float* __restrict__ out) {
    int w = threadIdx.x >> 6, lane = threadIdx.x & 63;
    int node = blockIdx.x * 4 + w;
    if (node >= n) return;
    int beg = offsets[node], end = offsets[node + 1];
    float dn = dinv[node];
    float a = 0.f;
    for (int e2 = beg; e2 < end; ++e2) {
        int eid = eperm[e2];
        int s = src[eid];
        a += (-dn * dinv[s]) * x[s * DD + lane];
    }
    out[node * DD + lane] = alpha * a + beta * prev[node * DD + lane];
}

// ---------- QKV projections: [h|p] @ W{Q,K,V} ----------
__global__ void k_qkv(const float* __restrict__ h, const float* __restrict__ p,
                      const float* __restrict__ WQ, const float* __restrict__ WK,
                      const float* __restrict__ WV, int n,
                      float* __restrict__ Qh, float* __restrict__ Kh, float* __restrict__ Vh) {
    __shared__ float hp[4][128];
    int w = threadIdx.x >> 6, lane = threadIdx.x & 63;
    int node = blockIdx.x * 4 + w;
    if (node < n) {
        hp[w][lane] = h[node * DD + lane];
        hp[w][64 + lane] = p[node * DD + lane];
    }
    __syncthreads();
    if (node >= n) return;
    float q = 0.f, k = 0.f, v = 0.f;
#pragma unroll 8
    for (int i = 0; i < 128; ++i) {
        float x = hp[w][i];
        q += x * WQ[i * 64 + lane];
        k += x * WK[i * 64 + lane];
        v += x * WV[i * 64 + lane];
    }
    Qh[node * 64 + lane] = q;
    Kh[node * 64 + lane] = k;
    Vh[node * 64 + lane] = v;
}

// ---------- per-edge scores: Eh = e@WE, s = exp(clip(sum_d K*Q/sqrt(8)*Eh)) ----------
__global__ void k_score(const float* __restrict__ efeat, const float* __restrict__ WE,
                        const int* __restrict__ src, const int* __restrict__ dst,
                        const float* __restrict__ Qh, const float* __restrict__ Kh,
                        int E, float* __restrict__ ss) {
    __shared__ float WEs[64 * 64];
    __shared__ float erow[4][64];
    int t = threadIdx.x;
    for (int i = t; i < 4096; i += 256) WEs[i] = WE[i];
    __syncthreads();
    int w = t >> 6, lane = t & 63;
    const float invs = 0.35355339059327373f;  // 1/sqrt(8)
    for (int ei = 0; ei < 8; ++ei) {
        __syncthreads();  // WAR: previous iter reads done
        int edge = blockIdx.x * 32 + w * 8 + ei;
        if (edge < E) erow[w][lane] = efeat[edge * 64 + lane];
        __syncthreads();  // RAW
        if (edge < E) {
            float Ehv = 0.f;
#pragma unroll 8
            for (int j = 0; j < 64; ++j) Ehv += erow[w][j] * WEs[j * 64 + lane];
            int s_ = src[edge], t_ = dst[edge];
            float part = Kh[s_ * 64 + lane] * Qh[t_ * 64 + lane] * Ehv * invs;
            part += __shfl_xor(part, 1, 64);
            part += __shfl_xor(part, 2, 64);
            part += __shfl_xor(part, 4, 64);
            float sc = expf(fminf(fmaxf(part, -5.0f), 5.0f));
            if ((lane & 7) == 0) ss[edge * HH + (lane >> 3)] = sc;
        }
    }
}

// ---------- attention aggregation per node ----------
__global__ void k_attn_agg(const int* __restrict__ offsets, const int* __restrict__ eperm,
                           const int* __restrict__ src, const float* __restrict__ Vh,
                           const float* __restrict__ ss, int n, float* __restrict__ out) {
    int w = threadIdx.x >> 6, lane = threadIdx.x & 63;
    int node = blockIdx.x * 4 + w;
    if (node >= n) return;
    int beg = offsets[node], end = offsets[node + 1];
    int hh = lane >> 3;
    float aV = 0.f, aZ = 0.f;
    for (int e2 = beg; e2 < end; ++e2) {
        int eid = eperm[e2];
        int s = src[eid];
        float sv = ss[eid * HH + hh];
        aV += sv * Vh[s * 64 + lane];
        aZ += sv;
    }
    out[node * 192 + 128 + lane] = aV / (aZ + 1e-6f);
}

// ---------- output: cheb (sum_k fc_k * Tx_k @ Wc_k + bc) and gcn (agg@Wg + bg) ----------
__global__ void k_out(const float* __restrict__ Tx0, const float* __restrict__ Tx1,
                      const float* __restrict__ Tx2, const float* __restrict__ Tx3,
                      const float* __restrict__ aggG, const float* __restrict__ fc,
                      const float* __restrict__ Wc, const float* __restrict__ bc,
                      const float* __restrict__ Wg, const float* __restrict__ bg,
                      int n, float* __restrict__ out) {
    __shared__ float sT[KORD][32][64];
    __shared__ float sA[32][64];
    int base = blockIdx.x * 32;
    int t = threadIdx.x;
    for (int idx = t; idx < 2048; idx += 256) {
        int ni = idx >> 6, j = idx & 63;
        int node = base + ni;
        if (node < n) {
            sT[0][ni][j] = fc[node] * Tx0[node * 64 + j];
            sT[1][ni][j] = fc[n + node] * Tx1[node * 64 + j];
            sT[2][ni][j] = fc[2 * n + node] * Tx2[node * 64 + j];
            sT[3][ni][j] = fc[3 * n + node] * Tx3[node * 64 + j];
            sA[ni][j] = aggG[node * 64 + j];
        } else {
            sT[0][ni][j] = 0.f; sT[1][ni][j] = 0.f;
            sT[2][ni][j] = 0.f; sT[3][ni][j] = 0.f;
            sA[ni][j] = 0.f;
        }
    }
    __syncthreads();
    int w = t >> 6, lane = t & 63;
    float acc[8];
#pragma unroll
    for (int i = 0; i < 8; ++i) acc[i] = 0.f;
#pragma unroll
    for (int k = 0; k < KORD; ++k) {
        for (int j = 0; j < 64; ++j) {
            float wv = Wc[k * 4096 + j * 64 + lane];
#pragma unroll
            for (int i = 0; i < 8; ++i) acc[i] += sT[k][w * 8 + i][j] * wv;
        }
    }
    float acc2[8];
#pragma unroll
    for (int i = 0; i < 8; ++i) acc2[i] = 0.f;
    for (int j = 0; j < 64; ++j) {
        float wv = Wg[j * 64 + lane];
#pragma unroll
        for (int i = 0; i < 8; ++i) acc2[i] += sA[w * 8 + i][j] * wv;
    }
    float bcv = bc[lane], bgv = bg[lane];
#pragma unroll
    for (int i = 0; i < 8; ++i) {
        int node = base + w * 8 + i;
        if (node < n) {
            out[node * 192 + lane] = acc[i] + bcv;
            out[node * 192 + 64 + lane] = acc2[i] + bgv;
        }
    }
}

extern "C" void kernel_launch(void* const* d_in, const int* in_sizes, int n_in,
                              void* d_out, int out_size, void* d_ws, size_t ws_size,
                              hipStream_t stream) {
    const float* h  = (const float*)d_in[0];
    const float* p  = (const float*)d_in[1];
    const float* ef = (const float*)d_in[2];
    const float* ew = (const float*)d_in[3];
    const float* fc = (const float*)d_in[4];
    const int* esrc = (const int*)d_in[5];
    const int* edst = (const int*)d_in[6];
    const float* Wc = (const float*)d_in[7];
    const float* bc = (const float*)d_in[8];
    const float* Wg = (const float*)d_in[9];
    const float* bg = (const float*)d_in[10];
    const float* WQ = (const float*)d_in[11];
    const float* WK = (const float*)d_in[12];
    const float* WV = (const float*)d_in[13];
    const float* WE = (const float*)d_in[14];

    const int n = in_sizes[0] / DD;   // 50000
    const int E = in_sizes[5];        // 800000
    float* out = (float*)d_out;

    char* wsp = (char*)d_ws;
    size_t o = 0;
    auto alloc = [&](size_t bytes) -> void* {
        void* r = (void*)(wsp + o);
        o = (o + bytes + 255) & ~(size_t)255;
        return r;
    };
    int* deg     = (int*)alloc((size_t)n * 4);
    int* offsets = (int*)alloc((size_t)(n + 1) * 4);
    int* cursor  = (int*)alloc((size_t)n * 4);
    int* eperm   = (int*)alloc((size_t)E * 4);
    int* bsum    = (int*)alloc(1024 * 4);
    float* dinv  = (float*)alloc((size_t)n * 4);
    float* Tx1   = (float*)alloc((size_t)n * DD * 4);
    float* Tx2   = (float*)alloc((size_t)n * DD * 4);
    float* Tx3   = (float*)alloc((size_t)n * DD * 4);
    float* agg   = (float*)alloc((size_t)n * DD * 4);
    float* Qh    = (float*)alloc((size_t)n * DD * 4);
    float* Kh    = (float*)alloc((size_t)n * DD * 4);
    float* Vh    = (float*)alloc((size_t)n * DD * 4);
    float* ss    = (float*)alloc((size_t)E * HH * 4);
    (void)ws_size; (void)n_in; (void)out_size;

    hipMemsetAsync(deg, 0, (size_t)n * 4, stream);

    int nb = (n + 255) / 256;
    k_count<<<(E + 255) / 256, 256, 0, stream>>>(edst, E, deg);
    k_blocksum<<<nb, 256, 0, stream>>>(deg, n, bsum);
    k_scan_bsum<<<1, 256, 0, stream>>>(bsum, nb);
    k_scan_final<<<nb, 256, 0, stream>>>(deg, bsum, n, E, offsets, cursor, dinv);
    k_scatter<<<(E + 255) / 256, 256, 0, stream>>>(edst, E, cursor, eperm);

    k_pass1<<<(n + 3) / 4, 256, 0, stream>>>(offsets, eperm, esrc, ew, dinv, h, n, Tx1, agg);
    k_lap<<<(n + 3) / 4, 256, 0, stream>>>(offsets, eperm, esrc, dinv, Tx1, h, 2.0f, -1.0f, n, Tx2);
    k_lap<<<(n + 3) / 4, 256, 0, stream>>>(offsets, eperm, esrc, dinv, Tx2, Tx1, 2.0f, -1.0f, n, Tx3);

    k_qkv<<<(n + 3) / 4, 256, 0, stream>>>(h, p, WQ, WK, WV, n, Qh, Kh, Vh);
    k_score<<<(E + 31) / 32, 256, 0, stream>>>(ef, WE, esrc, edst, Qh, Kh, E, ss);
    k_attn_agg<<<(n + 3) / 4, 256, 0, stream>>>(offsets, eperm, esrc, Vh, ss, n, out);

    k_out<<<(n + 31) / 32, 256, 0, stream>>>(h, Tx1, Tx2, Tx3, agg, fc, Wc, bc, Wg, bg, n, out);
}

// Round 2
// 871.361 us; speedup vs baseline: 1.2884x; 1.2884x over previous
//
#include <hip/hip_runtime.h>
#include <math.h>

#define DD 64
#define HH 8
#define KORD 4

// ---------- CSR build ----------
__global__ void k_count(const int* __restrict__ dst, int E, int* __restrict__ deg) {
    int i = blockIdx.x * 256 + threadIdx.x;
    if (i < E) atomicAdd(&deg[dst[i]], 1);
}

__global__ void k_blocksum(const int* __restrict__ deg, int n, int* __restrict__ bsum) {
    __shared__ int s[256];
    int i = blockIdx.x * 256 + threadIdx.x;
    s[threadIdx.x] = (i < n) ? deg[i] : 0;
    __syncthreads();
    for (int off = 128; off > 0; off >>= 1) {
        if (threadIdx.x < off) s[threadIdx.x] += s[threadIdx.x + off];
        __syncthreads();
    }
    if (threadIdx.x == 0) bsum[blockIdx.x] = s[0];
}

__global__ void k_scan_bsum(int* __restrict__ bsum, int nb) {
    __shared__ int s[256];
    int t = threadIdx.x;
    int v = (t < nb) ? bsum[t] : 0;
    s[t] = v;
    __syncthreads();
    for (int off = 1; off < 256; off <<= 1) {
        int tmp = (t >= off) ? s[t - off] : 0;
        __syncthreads();
        s[t] += tmp;
        __syncthreads();
    }
    if (t < nb) bsum[t] = s[t] - v;  // exclusive
}

__global__ void k_scan_final(const int* __restrict__ deg, const int* __restrict__ bsum,
                             int n, int E, int* __restrict__ offsets,
                             int* __restrict__ cursor, float* __restrict__ dinv) {
    __shared__ int s[256];
    int t = threadIdx.x, i = blockIdx.x * 256 + t;
    int v = (i < n) ? deg[i] : 0;
    s[t] = v;
    __syncthreads();
    for (int off = 1; off < 256; off <<= 1) {
        int tmp = (t >= off) ? s[t - off] : 0;
        __syncthreads();
        s[t] += tmp;
        __syncthreads();
    }
    if (i < n) {
        int excl = s[t] - v + bsum[blockIdx.x];
        offsets[i] = excl;
        cursor[i] = excl;
        int dv = v < 1 ? 1 : v;
        dinv[i] = 1.0f / sqrtf((float)dv);
    }
    if (i == 0) offsets[n] = E;
}

// scatter: build dst-sorted edge arrays so downstream gathers have no indirection
__global__ void k_scatter(const int* __restrict__ dst, const int* __restrict__ src,
                          const float* __restrict__ ew, int E, int* __restrict__ cursor,
                          int* __restrict__ eperm, int* __restrict__ srcs,
                          float* __restrict__ ews) {
    int i = blockIdx.x * 256 + threadIdx.x;
    if (i < E) {
        int p = atomicAdd(&cursor[dst[i]], 1);
        eperm[p] = i;
        srcs[p] = src[i];
        ews[p] = ew[i];
    }
}

// WE^T for scalar-operand loads in k_score: WET[d][j] = WE[j][d]
__global__ void k_wet(const float* __restrict__ WE, float* __restrict__ WET) {
    for (int idx = threadIdx.x; idx < 4096; idx += 256) {
        int d = idx >> 6, j = idx & 63;
        WET[idx] = WE[j * 64 + d];
    }
}

// ---------- pass 1: Tx1 = lap_mul(h), agg = sum ew*h[src] ----------
__global__ void k_pass1(const int* __restrict__ offsets, const int* __restrict__ srcs,
                        const float* __restrict__ ews, const float* __restrict__ dinv,
                        const float* __restrict__ h, int n,
                        float* __restrict__ Tx1, float* __restrict__ agg) {
    int w = threadIdx.x >> 6, lane = threadIdx.x & 63;
    int node = blockIdx.x * 4 + w;
    if (node >= n) return;
    int beg = offsets[node], end = offsets[node + 1];
    float dn = dinv[node];
    float aL = 0.f, aG = 0.f;
    for (int e2 = beg; e2 < end; ++e2) {
        int s = srcs[e2];
        float v = h[s * DD + lane];
        aL += dinv[s] * v;
        aG += ews[e2] * v;
    }
    Tx1[node * DD + lane] = -dn * aL;
    agg[node * DD + lane] = aG;
}

// ---------- out = alpha * lap_mul(x) + beta * prev ----------
__global__ void k_lap(const int* __restrict__ offsets, const int* __restrict__ srcs,
                      const float* __restrict__ dinv, const float* __restrict__ x,
                      const float* __restrict__ prev, float alpha, float beta, int n,
                      float* __restrict__ out) {
    int w = threadIdx.x >> 6, lane = threadIdx.x & 63;
    int node = blockIdx.x * 4 + w;
    if (node >= n) return;
    int beg = offsets[node], end = offsets[node + 1];
    float dn = dinv[node];
    float a = 0.f;
    for (int e2 = beg; e2 < end; ++e2) {
        int s = srcs[e2];
        a += dinv[s] * x[s * DD + lane];
    }
    out[node * DD + lane] = alpha * (-dn * a) + beta * prev[node * DD + lane];
}

// ---------- QKV projections, 8 nodes per wave (weights reused 8x) ----------
__global__ void k_qkv(const float* __restrict__ h, const float* __restrict__ p,
                      const float* __restrict__ WQ, const float* __restrict__ WK,
                      const float* __restrict__ WV, int n,
                      float* __restrict__ Qh, float* __restrict__ Kh, float* __restrict__ Vh) {
    __shared__ float hp[32][128];
    int base = blockIdx.x * 32;
    int t = threadIdx.x;
    for (int idx = t; idx < 4096; idx += 256) {
        int ni = idx >> 7, j = idx & 127;
        int node = base + ni;
        float v = 0.f;
        if (node < n) v = (j < 64) ? h[node * 64 + j] : p[node * 64 + (j - 64)];
        hp[ni][j] = v;
    }
    __syncthreads();
    int w = t >> 6, lane = t & 63;
    float q[8], k[8], v[8];
#pragma unroll
    for (int r = 0; r < 8; ++r) { q[r] = 0.f; k[r] = 0.f; v[r] = 0.f; }
    for (int i = 0; i < 128; ++i) {
        float wq = WQ[i * 64 + lane], wk = WK[i * 64 + lane], wv = WV[i * 64 + lane];
#pragma unroll
        for (int r = 0; r < 8; ++r) {
            float x = hp[w * 8 + r][i];
            q[r] += x * wq; k[r] += x * wk; v[r] += x * wv;
        }
    }
#pragma unroll
    for (int r = 0; r < 8; ++r) {
        int node = base + w * 8 + r;
        if (node < n) {
            Qh[node * 64 + lane] = q[r];
            Kh[node * 64 + lane] = k[r];
            Vh[node * 64 + lane] = v[r];
        }
    }
}

// ---------- per-edge scores: thread-per-edge, e-row in VGPRs, WE^T via scalar loads ----------
__global__ __launch_bounds__(256) void k_score(
        const float* __restrict__ efeat, const float* __restrict__ WET,
        const int* __restrict__ src, const int* __restrict__ dst,
        const float* __restrict__ Qh, const float* __restrict__ Kh,
        int E, float* __restrict__ ss) {
    int edge = blockIdx.x * 256 + threadIdx.x;
    if (edge >= E) return;
    const float4* e4 = (const float4*)efeat + (size_t)edge * 16;
    float4 er[16];
#pragma unroll
    for (int q = 0; q < 16; ++q) er[q] = e4[q];
    int s_ = src[edge], t_ = dst[edge];
    const float4* Kp = (const float4*)Kh + (size_t)s_ * 16;
    const float4* Qp = (const float4*)Qh + (size_t)t_ * 16;
    const float4* W4 = (const float4*)WET;
    const float invs = 0.35355339059327373f;  // 1/sqrt(8)
#pragma unroll 1
    for (int h = 0; h < 8; ++h) {
        float4 kv0 = Kp[h * 2], kv1 = Kp[h * 2 + 1];
        float4 qv0 = Qp[h * 2], qv1 = Qp[h * 2 + 1];
        float G[8] = {kv0.x * qv0.x, kv0.y * qv0.y, kv0.z * qv0.z, kv0.w * qv0.w,
                      kv1.x * qv1.x, kv1.y * qv1.y, kv1.z * qv1.z, kv1.w * qv1.w};
        float sc = 0.f;
#pragma unroll
        for (int dd = 0; dd < 8; ++dd) {
            int d = h * 8 + dd;
            float eh = 0.f;
#pragma unroll
            for (int q = 0; q < 16; ++q) {
                float4 wv = W4[d * 16 + q];  // wave-uniform -> scalar load
                eh += er[q].x * wv.x + er[q].y * wv.y + er[q].z * wv.z + er[q].w * wv.w;
            }
            sc += G[dd] * eh;
        }
        sc = __expf(fminf(fmaxf(sc * invs, -5.0f), 5.0f));
        ss[(size_t)edge * HH + h] = sc;
    }
}

// ---------- attention aggregation per node ----------
__global__ void k_attn_agg(const int* __restrict__ offsets, const int* __restrict__ srcs,
                           const int* __restrict__ eperm, const float* __restrict__ Vh,
                           const float* __restrict__ ss, int n, float* __restrict__ out) {
    int w = threadIdx.x >> 6, lane = threadIdx.x & 63;
    int node = blockIdx.x * 4 + w;
    if (node >= n) return;
    int beg = offsets[node], end = offsets[node + 1];
    int hh = lane >> 3;
    float aV = 0.f, aZ = 0.f;
    for (int e2 = beg; e2 < end; ++e2) {
        int s = srcs[e2];
        int eid = eperm[e2];
        float sv = ss[(size_t)eid * HH + hh];
        aV += sv * Vh[s * 64 + lane];
        aZ += sv;
    }
    out[node * 192 + 128 + lane] = aV / (aZ + 1e-6f);
}

// ---------- output: cheb (sum_k fc_k * Tx_k @ Wc_k + bc) and gcn (agg@Wg + bg) ----------
__global__ void k_out(const float* __restrict__ Tx0, const float* __restrict__ Tx1,
                      const float* __restrict__ Tx2, const float* __restrict__ Tx3,
                      const float* __restrict__ aggG, const float* __restrict__ fc,
                      const float* __restrict__ Wc, const float* __restrict__ bc,
                      const float* __restrict__ Wg, const float* __restrict__ bg,
                      int n, float* __restrict__ out) {
    __shared__ float sT[KORD][32][64];
    __shared__ float sA[32][64];
    int base = blockIdx.x * 32;
    int t = threadIdx.x;
    for (int idx = t; idx < 2048; idx += 256) {
        int ni = idx >> 6, j = idx & 63;
        int node = base + ni;
        if (node < n) {
            sT[0][ni][j] = fc[node] * Tx0[node * 64 + j];
            sT[1][ni][j] = fc[n + node] * Tx1[node * 64 + j];
            sT[2][ni][j] = fc[2 * n + node] * Tx2[node * 64 + j];
            sT[3][ni][j] = fc[3 * n + node] * Tx3[node * 64 + j];
            sA[ni][j] = aggG[node * 64 + j];
        } else {
            sT[0][ni][j] = 0.f; sT[1][ni][j] = 0.f;
            sT[2][ni][j] = 0.f; sT[3][ni][j] = 0.f;
            sA[ni][j] = 0.f;
        }
    }
    __syncthreads();
    int w = t >> 6, lane = t & 63;
    float acc[8];
#pragma unroll
    for (int i = 0; i < 8; ++i) acc[i] = 0.f;
#pragma unroll
    for (int k = 0; k < KORD; ++k) {
        for (int j = 0; j < 64; ++j) {
            float wv = Wc[k * 4096 + j * 64 + lane];
#pragma unroll
            for (int i = 0; i < 8; ++i) acc[i] += sT[k][w * 8 + i][j] * wv;
        }
    }
    float acc2[8];
#pragma unroll
    for (int i = 0; i < 8; ++i) acc2[i] = 0.f;
    for (int j = 0; j < 64; ++j) {
        float wv = Wg[j * 64 + lane];
#pragma unroll
        for (int i = 0; i < 8; ++i) acc2[i] += sA[w * 8 + i][j] * wv;
    }
    float bcv = bc[lane], bgv = bg[lane];
#pragma unroll
    for (int i = 0; i < 8; ++i) {
        int node = base + w * 8 + i;
        if (node < n) {
            out[node * 192 + lane] = acc[i] + bcv;
            out[node * 192 + 64 + lane] = acc2[i] + bgv;
        }
    }
}

extern "C" void kernel_launch(void* const* d_in, const int* in_sizes, int n_in,
                              void* d_out, int out_size, void* d_ws, size_t ws_size,
                              hipStream_t stream) {
    const float* h  = (const float*)d_in[0];
    const float* p  = (const float*)d_in[1];
    const float* ef = (const float*)d_in[2];
    const float* ew = (const float*)d_in[3];
    const float* fc = (const float*)d_in[4];
    const int* esrc = (const int*)d_in[5];
    const int* edst = (const int*)d_in[6];
    const float* Wc = (const float*)d_in[7];
    const float* bc = (const float*)d_in[8];
    const float* Wg = (const float*)d_in[9];
    const float* bg = (const float*)d_in[10];
    const float* WQ = (const float*)d_in[11];
    const float* WK = (const float*)d_in[12];
    const float* WV = (const float*)d_in[13];
    const float* WE = (const float*)d_in[14];

    const int n = in_sizes[0] / DD;   // 50000
    const int E = in_sizes[5];        // 800000
    float* out = (float*)d_out;

    char* wsp = (char*)d_ws;
    size_t o = 0;
    auto alloc = [&](size_t bytes) -> void* {
        void* r = (void*)(wsp + o);
        o = (o + bytes + 255) & ~(size_t)255;
        return r;
    };
    int* deg     = (int*)alloc((size_t)n * 4);
    int* offsets = (int*)alloc((size_t)(n + 1) * 4);
    int* cursor  = (int*)alloc((size_t)n * 4);
    int* eperm   = (int*)alloc((size_t)E * 4);
    int* srcs    = (int*)alloc((size_t)E * 4);
    float* ews   = (float*)alloc((size_t)E * 4);
    int* bsum    = (int*)alloc(1024 * 4);
    float* dinv  = (float*)alloc((size_t)n * 4);
    float* WET   = (float*)alloc(4096 * 4);
    float* Tx1   = (float*)alloc((size_t)n * DD * 4);
    float* Tx2   = (float*)alloc((size_t)n * DD * 4);
    float* Tx3   = (float*)alloc((size_t)n * DD * 4);
    float* agg   = (float*)alloc((size_t)n * DD * 4);
    float* Qh    = (float*)alloc((size_t)n * DD * 4);
    float* Kh    = (float*)alloc((size_t)n * DD * 4);
    float* Vh    = (float*)alloc((size_t)n * DD * 4);
    float* ss    = (float*)alloc((size_t)E * HH * 4);
    (void)ws_size; (void)n_in; (void)out_size;

    hipMemsetAsync(deg, 0, (size_t)n * 4, stream);

    int nb = (n + 255) / 256;
    k_count<<<(E + 255) / 256, 256, 0, stream>>>(edst, E, deg);
    k_blocksum<<<nb, 256, 0, stream>>>(deg, n, bsum);
    k_scan_bsum<<<1, 256, 0, stream>>>(bsum, nb);
    k_scan_final<<<nb, 256, 0, stream>>>(deg, bsum, n, E, offsets, cursor, dinv);
    k_scatter<<<(E + 255) / 256, 256, 0, stream>>>(edst, esrc, ew, E, cursor, eperm, srcs, ews);
    k_wet<<<1, 256, 0, stream>>>(WE, WET);

    k_pass1<<<(n + 3) / 4, 256, 0, stream>>>(offsets, srcs, ews, dinv, h, n, Tx1, agg);
    k_lap<<<(n + 3) / 4, 256, 0, stream>>>(offsets, srcs, dinv, Tx1, h, 2.0f, -1.0f, n, Tx2);
    k_lap<<<(n + 3) / 4, 256, 0, stream>>>(offsets, srcs, dinv, Tx2, Tx1, 2.0f, -1.0f, n, Tx3);

    k_qkv<<<(n + 31) / 32, 256, 0, stream>>>(h, p, WQ, WK, WV, n, Qh, Kh, Vh);
    k_score<<<(E + 255) / 256, 256, 0, stream>>>(ef, WET, esrc, edst, Qh, Kh, E, ss);
    k_attn_agg<<<(n + 3) / 4, 256, 0, stream>>>(offsets, srcs, eperm, Vh, ss, n, out);

    k_out<<<(n + 31) / 32, 256, 0, stream>>>(h, Tx1, Tx2, Tx3, agg, fc, Wc, bc, Wg, bg, n, out);
}